// Round 2
// baseline (4937.903 us; speedup 1.0000x reference)
//
#include <hip/hip_runtime.h>

#define NPTS 8192
#define NB 8
#define NS 2048
#define NK 32
// channel sizes
#define C0 67
#define C1 64
#define C2 64
#define C3 128
#define NTOT (NB*NS*NK)   // 524288 rows

// ---------------------------------------------------------------------------
// FPS: one block (512 thr) per batch. Exact np-f32 semantics:
//   d = ((dx*dx + dy*dy) + dz*dz)  (rn ops, no fma), mind = fminf(mind,d),
//   argmax = first occurrence of max (smallest index on exact float ties).
// Argmax via monotone packed u64 key: hi = float bits of v (v>=0 so order-
// preserving), lo = 8191-n (ties -> smallest n). Wave butterfly on the key;
// wave-winner lane writes (key, its coords) to an 8-slot LDS table
// (double-buffered by s&1 -> ONE barrier/step); all lanes scan the 8 slots
// in registers; global-winner lane stores new_xyz[s] directly.
// Also computes pp[n] = |p|^2 (same rn order) for ball query.
// ---------------------------------------------------------------------------
__global__ __launch_bounds__(512) void k_fps(const float* __restrict__ xyz,
                                             float* __restrict__ pp,
                                             float* __restrict__ newxyz) {
  const int b = blockIdx.x, tid = threadIdx.x;
  const int wv = tid >> 6;
  __shared__ uint4 sA[2][8];   // khi, klo, bits(x), bits(y)
  __shared__ unsigned sB[2][8]; // bits(z)
  __shared__ float s_init[3];
  const float* Xb = xyz + (size_t)b * NPTS * 3;
  float px[16], py[16], pz[16], mind[16];
#pragma unroll
  for (int k = 0; k < 16; k++) {
    int n = (k << 9) | tid;
    float x = Xb[n*3+0], y = Xb[n*3+1], z = Xb[n*3+2];
    px[k]=x; py[k]=y; pz[k]=z;
    pp[b*NPTS + n] = __fadd_rn(__fadd_rn(__fmul_rn(x,x), __fmul_rn(y,y)), __fmul_rn(z,z));
    mind[k] = 1e10f;
  }
  if (tid == 0) { s_init[0]=px[0]; s_init[1]=py[0]; s_init[2]=pz[0]; }
  __syncthreads();
  float lx = s_init[0], ly = s_init[1], lz = s_init[2];
  if (tid == 0) {
    float* o = newxyz + (size_t)b*NS*3;
    o[0]=lx; o[1]=ly; o[2]=lz;
  }
  for (int s = 1; s < NS; s++) {
    float v = -1.0f;
#pragma unroll
    for (int k = 0; k < 16; k++) {
      float dx = __fsub_rn(px[k], lx);
      float dy = __fsub_rn(py[k], ly);
      float dz = __fsub_rn(pz[k], lz);
      float d = __fadd_rn(__fadd_rn(__fmul_rn(dx,dx), __fmul_rn(dy,dy)), __fmul_rn(dz,dz));
      float m = fminf(mind[k], d);
      mind[k] = m;
      v = fmaxf(v, m);
    }
    // recover smallest k with mind[k]==v (first-occurrence semantics)
    int kk = 15;
#pragma unroll
    for (int k = 14; k >= 0; k--) if (mind[k] == v) kk = k;
    int n = (kk << 9) | tid;
    unsigned mhi = __float_as_uint(v);
    unsigned mlo = (unsigned)(8191 - n);
    unsigned khi = mhi, klo = mlo;
#pragma unroll
    for (int off = 1; off < 64; off <<= 1) {
      unsigned ohi = __shfl_xor(khi, off, 64);
      unsigned olo = __shfl_xor(klo, off, 64);
      bool gt = (ohi > khi) || (ohi == khi && olo > klo);
      khi = gt ? ohi : khi;
      klo = gt ? olo : klo;
    }
    int buf = s & 1;
    if (khi == mhi && klo == mlo) {  // unique wave-winner lane
      sA[buf][wv] = make_uint4(khi, klo, __float_as_uint(px[kk]), __float_as_uint(py[kk]));
      sB[buf][wv] = __float_as_uint(pz[kk]);
    }
    __syncthreads();
    uint4 bbA = sA[buf][0]; unsigned bbz = sB[buf][0];
#pragma unroll
    for (int j = 1; j < 8; j++) {
      uint4 t = sA[buf][j]; unsigned tz = sB[buf][j];
      bool gt = (t.x > bbA.x) || (t.x == bbA.x && t.y > bbA.y);
      if (gt) { bbA = t; bbz = tz; }
    }
    lx = __uint_as_float(bbA.z);
    ly = __uint_as_float(bbA.w);
    lz = __uint_as_float(bbz);
    if (bbA.x == mhi && bbA.y == mlo) {  // global winner lane writes output
      float* o = newxyz + ((size_t)b*NS + s)*3;
      o[0]=lx; o[1]=ly; o[2]=lz;
    }
  }
}

// ---------------------------------------------------------------------------
// Ball query: one wave per centroid. Exact np-f32 expanded distance:
//   d2 = (qq + pp) - 2*((cx*x + cy*y) + cz*z), inside iff d2 <= 0.0625f.
// First NK in-index-order indices; pad with first found.
// ---------------------------------------------------------------------------
__global__ __launch_bounds__(256) void k_bq(const float* __restrict__ xyz,
                                            const float* __restrict__ pp,
                                            const float* __restrict__ newxyz,
                                            int* __restrict__ idx) {
  int wv = (blockIdx.x << 2) | (threadIdx.x >> 6);   // 0..16383
  int lane = threadIdx.x & 63;
  int b = wv >> 11;
  const float* c3 = newxyz + (size_t)wv * 3;
  float cx = c3[0], cy = c3[1], cz = c3[2];
  float qq = __fadd_rn(__fadd_rn(__fmul_rn(cx,cx), __fmul_rn(cy,cy)), __fmul_rn(cz,cz));
  const float* Xb = xyz + (size_t)b * NPTS * 3;
  const float* Pb = pp + b * NPTS;
  int* out = idx + (size_t)wv * NK;
  int cnt = 0, first = 0;
  for (int j0 = 0; j0 < NPTS; j0 += 64) {
    int n = j0 + lane;
    float x = Xb[n*3+0], y = Xb[n*3+1], z = Xb[n*3+2];
    float dot = __fadd_rn(__fadd_rn(__fmul_rn(cx,x), __fmul_rn(cy,y)), __fmul_rn(cz,z));
    float d2 = __fsub_rn(__fadd_rn(qq, Pb[n]), __fmul_rn(2.0f, dot));
    bool in = (d2 <= 0.0625f);
    unsigned long long bal = __ballot(in);
    if (cnt == 0 && bal) first = j0 + (int)__builtin_ctzll(bal);
    int c = (int)__popcll(bal);
    if (in) {
      int pos = cnt + (int)__popcll(bal & ((1ull << lane) - 1ull));
      if (pos < NK) out[pos] = n;
    }
    cnt += c;
    if (cnt >= NK) break;
  }
  if (cnt < NK) {
    if (lane >= cnt && lane < NK) out[lane] = first;
  }
}

// ---------------------------------------------------------------------------
// Gather helper: builds feat[j][r] tile (j = channel 0..66, r = row 0..31)
// in LDS for group gid. feat[0..2][r] = xyz[idx]-center; feat[3+c][r]=points.
// ---------------------------------------------------------------------------
#define GATHER_GROUP(gid_, b_)                                                   \
  do {                                                                           \
    if (tid < 32) s_idx[tid] = idx[(size_t)(gid_)*NK + tid];                     \
    if (tid < 3)  s_c[tid]   = newxyz[(size_t)(gid_)*3 + tid];                   \
    __syncthreads();                                                             \
    if (tid < 32) {                                                              \
      const float* p = &xyz[((size_t)(b_)*NPTS + s_idx[tid])*3];                 \
      feat[0*32+tid] = p[0] - s_c[0];                                            \
      feat[1*32+tid] = p[1] - s_c[1];                                            \
      feat[2*32+tid] = p[2] - s_c[2];                                            \
    }                                                                            \
    {                                                                            \
      int r_ = tid & 31, cq_ = tid >> 5;                                         \
      const float* pr = &pts[((size_t)(b_)*NPTS + s_idx[r_])*64 + cq_*8];        \
      float4 A_ = *(const float4*)pr;                                            \
      float4 B_ = *(const float4*)(pr + 4);                                      \
      feat[(3+cq_*8+0)*32 + r_] = A_.x;                                          \
      feat[(3+cq_*8+1)*32 + r_] = A_.y;                                          \
      feat[(3+cq_*8+2)*32 + r_] = A_.z;                                          \
      feat[(3+cq_*8+3)*32 + r_] = A_.w;                                          \
      feat[(3+cq_*8+4)*32 + r_] = B_.x;                                          \
      feat[(3+cq_*8+5)*32 + r_] = B_.y;                                          \
      feat[(3+cq_*8+6)*32 + r_] = B_.z;                                          \
      feat[(3+cq_*8+7)*32 + r_] = B_.w;                                          \
    }                                                                            \
    __syncthreads();                                                             \
  } while (0)

// ---------------------------------------------------------------------------
// Pass A: layer-0 GEMM (discard values), accumulate per-channel sum/sumsq.
// grid 512 x 256thr, 32 groups/block. ALL 256 threads: 4 rows x 2 cols.
// ---------------------------------------------------------------------------
__global__ __launch_bounds__(256) void k_l0stats(const float* __restrict__ xyz,
                                                 const float* __restrict__ pts,
                                                 const float* __restrict__ newxyz,
                                                 const int* __restrict__ idx,
                                                 const float* __restrict__ w0,
                                                 float* __restrict__ partials) {
  __shared__ __align__(16) float w0t[C0*64];
  __shared__ __align__(16) float feat[C0*32];
  __shared__ int s_idx[32];
  __shared__ float s_c[3];
  int tid = threadIdx.x;
  for (int t = tid; t < C0*64; t += 256) { int j = t >> 6, c = t & 63; w0t[t] = w0[c*C0 + j]; }
  int rt = tid & 7, ct = tid >> 3;          // rows rt*4.., cols ct*2..
  float s0[2] = {0,0}, q0[2] = {0,0};
  for (int g = 0; g < 32; g++) {
    int gid = blockIdx.x * 32 + g;
    int b = gid >> 11;
    __syncthreads();
    GATHER_GROUP(gid, b);
    float acc[4][2] = {};
    for (int j = 0; j < C0; j++) {
      float4 av = *(const float4*)&feat[j*32 + rt*4];
      float2 wv = *(const float2*)&w0t[j*64 + ct*2];
      float aa[4] = {av.x, av.y, av.z, av.w};
#pragma unroll
      for (int r = 0; r < 4; r++) {
        acc[r][0] = fmaf(aa[r], wv.x, acc[r][0]);
        acc[r][1] = fmaf(aa[r], wv.y, acc[r][1]);
      }
    }
#pragma unroll
    for (int r = 0; r < 4; r++)
#pragma unroll
      for (int u = 0; u < 2; u++) { float x = acc[r][u]; s0[u] += x; q0[u] = fmaf(x, x, q0[u]); }
  }
#pragma unroll
  for (int off = 1; off < 8; off <<= 1) {
#pragma unroll
    for (int u = 0; u < 2; u++) { s0[u] += __shfl_xor(s0[u], off, 64); q0[u] += __shfl_xor(q0[u], off, 64); }
  }
  if (rt == 0) {
#pragma unroll
    for (int u = 0; u < 2; u++) {
      size_t o = ((size_t)blockIdx.x * 128 + ct*2 + u) * 2;
      partials[o] = s0[u]; partials[o+1] = q0[u];
    }
  }
}

// ---------------------------------------------------------------------------
// Pass B: recompute L0, apply BN0+ReLU, L1 GEMM, accumulate stats1.
// ALL 256 threads: 4 rows x 2 cols per stage.
// ---------------------------------------------------------------------------
__global__ __launch_bounds__(256) void k_l1stats(const float* __restrict__ xyz,
                                                 const float* __restrict__ pts,
                                                 const float* __restrict__ newxyz,
                                                 const int* __restrict__ idx,
                                                 const float* __restrict__ w0,
                                                 const float* __restrict__ w1,
                                                 const float* __restrict__ statsF,
                                                 float* __restrict__ partials) {
  __shared__ __align__(16) float w0t[C0*64];
  __shared__ __align__(16) float w1t[64*64];
  __shared__ __align__(16) float feat[C0*32];
  __shared__ __align__(16) float x0n[64*32];
  __shared__ int s_idx[32];
  __shared__ float s_c[3];
  int tid = threadIdx.x;
  for (int t = tid; t < C0*64; t += 256) { int j = t >> 6, c = t & 63; w0t[t] = w0[c*C0 + j]; }
  for (int t = tid; t < 64*64; t += 256) { int j = t >> 6, c = t & 63; w1t[t] = w1[c*64 + j]; }
  int rt = tid & 7, ct = tid >> 3;
  float a0[2], b0v[2];
#pragma unroll
  for (int u = 0; u < 2; u++) {
    a0[u]  = statsF[(0*128 + ct*2 + u)*2];
    b0v[u] = statsF[(0*128 + ct*2 + u)*2 + 1];
  }
  float s1[2] = {0,0}, q1[2] = {0,0};
  for (int g = 0; g < 32; g++) {
    int gid = blockIdx.x * 32 + g;
    int b = gid >> 11;
    __syncthreads();
    GATHER_GROUP(gid, b);
    {
      float acc[4][2] = {};
      for (int j = 0; j < C0; j++) {
        float4 av = *(const float4*)&feat[j*32 + rt*4];
        float2 wv = *(const float2*)&w0t[j*64 + ct*2];
        float aa[4] = {av.x, av.y, av.z, av.w};
#pragma unroll
        for (int r = 0; r < 4; r++) {
          acc[r][0] = fmaf(aa[r], wv.x, acc[r][0]);
          acc[r][1] = fmaf(aa[r], wv.y, acc[r][1]);
        }
      }
#pragma unroll
      for (int u = 0; u < 2; u++) {
        float4 st;
        st.x = fmaxf(0.f, fmaf(acc[0][u], a0[u], b0v[u]));
        st.y = fmaxf(0.f, fmaf(acc[1][u], a0[u], b0v[u]));
        st.z = fmaxf(0.f, fmaf(acc[2][u], a0[u], b0v[u]));
        st.w = fmaxf(0.f, fmaf(acc[3][u], a0[u], b0v[u]));
        *(float4*)&x0n[(ct*2 + u)*32 + rt*4] = st;
      }
    }
    __syncthreads();
    {
      float acc[4][2] = {};
      for (int j = 0; j < 64; j++) {
        float4 av = *(const float4*)&x0n[j*32 + rt*4];
        float2 wv = *(const float2*)&w1t[j*64 + ct*2];
        float aa[4] = {av.x, av.y, av.z, av.w};
#pragma unroll
        for (int r = 0; r < 4; r++) {
          acc[r][0] = fmaf(aa[r], wv.x, acc[r][0]);
          acc[r][1] = fmaf(aa[r], wv.y, acc[r][1]);
        }
      }
#pragma unroll
      for (int r = 0; r < 4; r++)
#pragma unroll
        for (int u = 0; u < 2; u++) { float x = acc[r][u]; s1[u] += x; q1[u] = fmaf(x, x, q1[u]); }
    }
  }
#pragma unroll
  for (int off = 1; off < 8; off <<= 1) {
#pragma unroll
    for (int u = 0; u < 2; u++) { s1[u] += __shfl_xor(s1[u], off, 64); q1[u] += __shfl_xor(q1[u], off, 64); }
  }
  if (rt == 0) {
#pragma unroll
    for (int u = 0; u < 2; u++) {
      size_t o = ((size_t)blockIdx.x * 128 + ct*2 + u) * 2;
      partials[o] = s1[u]; partials[o+1] = q1[u];
    }
  }
}

// ---------------------------------------------------------------------------
// Pass C: recompute L0(BN0,ReLU), L1(BN1,ReLU), compute L2 pre-BN values:
// accumulate stats2 and per-(group,channel) max/min over the 32 rows.
// grid 256 x 256thr, 64 groups/block. ALL 256 threads active.
// ---------------------------------------------------------------------------
__global__ __launch_bounds__(256) void k_l2(const float* __restrict__ xyz,
                                            const float* __restrict__ pts,
                                            const float* __restrict__ newxyz,
                                            const int* __restrict__ idx,
                                            const float* __restrict__ w0,
                                            const float* __restrict__ w1,
                                            const float* __restrict__ w2,
                                            const float* __restrict__ statsF,
                                            float* __restrict__ partials,
                                            float* __restrict__ maxb,
                                            float* __restrict__ minb) {
  __shared__ __align__(16) float w0t[C0*64];
  __shared__ __align__(16) float w1t[64*64];
  __shared__ __align__(16) float w2t[64*128];
  __shared__ __align__(16) float feat[C0*32];
  __shared__ __align__(16) float x0n[64*32];
  __shared__ __align__(16) float x1n[64*32];
  __shared__ int s_idx[32];
  __shared__ float s_c[3];
  int tid = threadIdx.x;
  for (int t = tid; t < C0*64; t += 256) { int j = t >> 6, c = t & 63; w0t[t] = w0[c*C0 + j]; }
  for (int t = tid; t < 64*64; t += 256) { int j = t >> 6, c = t & 63; w1t[t] = w1[c*64 + j]; }
  for (int t = tid; t < 64*128; t += 256) { int j = t >> 7, c = t & 127; w2t[t] = w2[c*64 + j]; }
  int rt = tid & 7, ct = tid >> 3;   // rows rt*4.., L0/L1 cols ct*2.., L2 cols ct*4..
  float a0[2], b0v[2], a1[2], b1v[2];
#pragma unroll
  for (int u = 0; u < 2; u++) {
    a0[u]  = statsF[(0*128 + ct*2 + u)*2];
    b0v[u] = statsF[(0*128 + ct*2 + u)*2 + 1];
    a1[u]  = statsF[(1*128 + ct*2 + u)*2];
    b1v[u] = statsF[(1*128 + ct*2 + u)*2 + 1];
  }
  float s2[4] = {0,0,0,0}, q2[4] = {0,0,0,0};
  for (int g = 0; g < 64; g++) {
    int gid = blockIdx.x * 64 + g;
    int b = gid >> 11;
    __syncthreads();
    GATHER_GROUP(gid, b);
    {
      float acc[4][2] = {};
      for (int j = 0; j < C0; j++) {
        float4 av = *(const float4*)&feat[j*32 + rt*4];
        float2 wv = *(const float2*)&w0t[j*64 + ct*2];
        float aa[4] = {av.x, av.y, av.z, av.w};
#pragma unroll
        for (int r = 0; r < 4; r++) {
          acc[r][0] = fmaf(aa[r], wv.x, acc[r][0]);
          acc[r][1] = fmaf(aa[r], wv.y, acc[r][1]);
        }
      }
#pragma unroll
      for (int u = 0; u < 2; u++) {
        float4 st;
        st.x = fmaxf(0.f, fmaf(acc[0][u], a0[u], b0v[u]));
        st.y = fmaxf(0.f, fmaf(acc[1][u], a0[u], b0v[u]));
        st.z = fmaxf(0.f, fmaf(acc[2][u], a0[u], b0v[u]));
        st.w = fmaxf(0.f, fmaf(acc[3][u], a0[u], b0v[u]));
        *(float4*)&x0n[(ct*2 + u)*32 + rt*4] = st;
      }
    }
    __syncthreads();
    {
      float acc[4][2] = {};
      for (int j = 0; j < 64; j++) {
        float4 av = *(const float4*)&x0n[j*32 + rt*4];
        float2 wv = *(const float2*)&w1t[j*64 + ct*2];
        float aa[4] = {av.x, av.y, av.z, av.w};
#pragma unroll
        for (int r = 0; r < 4; r++) {
          acc[r][0] = fmaf(aa[r], wv.x, acc[r][0]);
          acc[r][1] = fmaf(aa[r], wv.y, acc[r][1]);
        }
      }
#pragma unroll
      for (int u = 0; u < 2; u++) {
        float4 st;
        st.x = fmaxf(0.f, fmaf(acc[0][u], a1[u], b1v[u]));
        st.y = fmaxf(0.f, fmaf(acc[1][u], a1[u], b1v[u]));
        st.z = fmaxf(0.f, fmaf(acc[2][u], a1[u], b1v[u]));
        st.w = fmaxf(0.f, fmaf(acc[3][u], a1[u], b1v[u]));
        *(float4*)&x1n[(ct*2 + u)*32 + rt*4] = st;
      }
    }
    __syncthreads();
    {  // L2: 4 rows x 4 cols per thread, cols ct*4..ct*4+3
      float acc[4][4] = {};
      for (int j = 0; j < 64; j++) {
        float4 av = *(const float4*)&x1n[j*32 + rt*4];
        float4 wvv = *(const float4*)&w2t[j*128 + ct*4];
        float aa[4] = {av.x, av.y, av.z, av.w};
        float ww[4] = {wvv.x, wvv.y, wvv.z, wvv.w};
#pragma unroll
        for (int r = 0; r < 4; r++)
#pragma unroll
          for (int u = 0; u < 4; u++) acc[r][u] = fmaf(aa[r], ww[u], acc[r][u]);
      }
      float mx[4], mn[4];
#pragma unroll
      for (int u = 0; u < 4; u++) {
        float x0 = acc[0][u], x1 = acc[1][u], x2 = acc[2][u], x3 = acc[3][u];
        s2[u] += ((x0 + x1) + (x2 + x3));
        q2[u] = fmaf(x0, x0, q2[u]); q2[u] = fmaf(x1, x1, q2[u]);
        q2[u] = fmaf(x2, x2, q2[u]); q2[u] = fmaf(x3, x3, q2[u]);
        mx[u] = fmaxf(fmaxf(x0, x1), fmaxf(x2, x3));
        mn[u] = fminf(fminf(x0, x1), fminf(x2, x3));
      }
#pragma unroll
      for (int off = 1; off < 8; off <<= 1) {
#pragma unroll
        for (int u = 0; u < 4; u++) {
          mx[u] = fmaxf(mx[u], __shfl_xor(mx[u], off, 64));
          mn[u] = fminf(mn[u], __shfl_xor(mn[u], off, 64));
        }
      }
      if (rt == 0) {
#pragma unroll
        for (int u = 0; u < 4; u++) {
          maxb[(size_t)gid*128 + ct*4 + u] = mx[u];
          minb[(size_t)gid*128 + ct*4 + u] = mn[u];
        }
      }
    }
  }
#pragma unroll
  for (int off = 1; off < 8; off <<= 1) {
#pragma unroll
    for (int u = 0; u < 4; u++) { s2[u] += __shfl_xor(s2[u], off, 64); q2[u] += __shfl_xor(q2[u], off, 64); }
  }
  if (rt == 0) {
#pragma unroll
    for (int u = 0; u < 4; u++) {
      size_t o = ((size_t)blockIdx.x * 128 + ct*4 + u) * 2;
      partials[o] = s2[u]; partials[o+1] = q2[u];
    }
  }
}

// ---------------------------------------------------------------------------
// Finalize BN stats: reduce per-block partials -> a = g/sqrt(var+eps),
// beta = be - mean*a. One block, C threads.
// ---------------------------------------------------------------------------
__global__ void k_fin(const float* __restrict__ partials, int nblk,
                      const float* __restrict__ g, const float* __restrict__ be,
                      float* __restrict__ statsF, int layer, int C) {
  int c = threadIdx.x;
  if (c >= C) return;
  float s = 0.f, q = 0.f;
  for (int k = 0; k < nblk; k++) {
    s += partials[((size_t)k * 128 + c) * 2];
    q += partials[((size_t)k * 128 + c) * 2 + 1];
  }
  const float inv = 1.0f / (float)NTOT;
  float mean = s * inv;
  float var = q * inv - mean * mean;
  float a = g[c] / sqrtf(var + 1e-5f);
  float bb = be[c] - mean * a;
  statsF[((size_t)layer * 128 + c) * 2]     = a;
  statsF[((size_t)layer * 128 + c) * 2 + 1] = bb;
}

// ---------------------------------------------------------------------------
// Pooling epilogue: pooled = relu(a*X + beta), X = (a>=0 ? max : min).
// (BN affine is monotone; relu is monotone -> maxpool commutes.)
// ---------------------------------------------------------------------------
__global__ __launch_bounds__(256) void k_pool(const float* __restrict__ maxb,
                                              const float* __restrict__ minb,
                                              const float* __restrict__ statsF,
                                              float* __restrict__ outp) {
  int t = blockIdx.x * 256 + threadIdx.x;   // < 16384*128
  int c = t & 127;
  float a  = statsF[(2*128 + c)*2];
  float bb = statsF[(2*128 + c)*2 + 1];
  float X = (a >= 0.f) ? maxb[t] : minb[t];
  outp[t] = fmaxf(0.f, fmaf(a, X, bb));
}

// ---------------------------------------------------------------------------
extern "C" void kernel_launch(void* const* d_in, const int* in_sizes, int n_in,
                              void* d_out, int out_size, void* d_ws, size_t ws_size,
                              hipStream_t stream) {
  (void)in_sizes; (void)n_in; (void)out_size; (void)ws_size;
  const float* xyz = (const float*)d_in[0];
  const float* pts = (const float*)d_in[1];
  const float* w0  = (const float*)d_in[2];
  const float* g0  = (const float*)d_in[4];
  const float* be0 = (const float*)d_in[5];
  const float* w1  = (const float*)d_in[6];
  const float* g1  = (const float*)d_in[8];
  const float* be1 = (const float*)d_in[9];
  const float* w2  = (const float*)d_in[10];
  const float* g2  = (const float*)d_in[12];
  const float* be2 = (const float*)d_in[13];

  float* out = (float*)d_out;
  float* newxyz = out;                    // [B,S,3]
  float* pooled = out + (size_t)NB*NS*3;  // [B,S,128]

  float* ws = (float*)d_ws;
  float* pp     = ws;                                 // 65536
  int*   idx    = (int*)(ws + 65536);                 // 524288 ints
  float* part   = ws + 65536 + 524288;                // 512*128*2 = 131072
  float* statsF = part + 131072;                      // 768
  float* maxb   = statsF + 768;                       // 2097152
  float* minb   = maxb + 2097152;                     // 2097152

  k_fps<<<NB, 512, 0, stream>>>(xyz, pp, newxyz);
  k_bq<<<4096, 256, 0, stream>>>(xyz, pp, newxyz, idx);
  k_l0stats<<<512, 256, 0, stream>>>(xyz, pts, newxyz, idx, w0, part);
  k_fin<<<1, 128, 0, stream>>>(part, 512, g0, be0, statsF, 0, 64);
  k_l1stats<<<512, 256, 0, stream>>>(xyz, pts, newxyz, idx, w0, w1, statsF, part);
  k_fin<<<1, 128, 0, stream>>>(part, 512, g1, be1, statsF, 1, 64);
  k_l2<<<256, 256, 0, stream>>>(xyz, pts, newxyz, idx, w0, w1, w2, statsF, part, maxb, minb);
  k_fin<<<1, 128, 0, stream>>>(part, 256, g2, be2, statsF, 2, 128);
  k_pool<<<8192, 256, 0, stream>>>(maxb, minb, statsF, pooled);
}

// Round 4
// 4137.406 us; speedup vs baseline: 1.1935x; 1.1935x over previous
//
#include <hip/hip_runtime.h>

#define NPTS 8192
#define NB 8
#define NS 2048
#define NK 32
// channel sizes
#define C0 67
#define C1 64
#define C2 64
#define C3 128
#define NTOT (NB*NS*NK)   // 524288 rows

// ---- DPP wave64 reduce helpers (VALU-speed cross-lane; result in lane 63) --
// template params => integer constant expressions for __builtin_amdgcn_update_dpp
template <int CTRL, int ROWM>
__device__ __forceinline__ float dpp_fmax_step(float x) {
  int yi = __builtin_amdgcn_update_dpp(__float_as_int(x), __float_as_int(x),
                                       CTRL, ROWM, 0xf, false);
  return fmaxf(x, __int_as_float(yi));
}
template <int CTRL, int ROWM>
__device__ __forceinline__ unsigned dpp_umin_step(unsigned x) {
  unsigned y = (unsigned)__builtin_amdgcn_update_dpp((int)x, (int)x,
                                                     CTRL, ROWM, 0xf, false);
  return (y < x) ? y : x;
}
__device__ __forceinline__ float wave_max_f32(float v) {
  v = dpp_fmax_step<0x111, 0xf>(v);  // row_shr:1
  v = dpp_fmax_step<0x112, 0xf>(v);  // row_shr:2
  v = dpp_fmax_step<0x114, 0xf>(v);  // row_shr:4
  v = dpp_fmax_step<0x118, 0xf>(v);  // row_shr:8
  v = dpp_fmax_step<0x142, 0xa>(v);  // row_bcast:15 -> rows 1,3
  v = dpp_fmax_step<0x143, 0xc>(v);  // row_bcast:31 -> rows 2,3
  return v;                           // lane 63 = wave max
}
__device__ __forceinline__ unsigned wave_min_u32(unsigned v) {
  v = dpp_umin_step<0x111, 0xf>(v);
  v = dpp_umin_step<0x112, 0xf>(v);
  v = dpp_umin_step<0x114, 0xf>(v);
  v = dpp_umin_step<0x118, 0xf>(v);
  v = dpp_umin_step<0x142, 0xa>(v);
  v = dpp_umin_step<0x143, 0xc>(v);
  return v;                           // lane 63 = wave min
}

// ---------------------------------------------------------------------------
// FPS: one block (512 thr) per batch. Exact np-f32 semantics:
//   d = ((dx*dx + dy*dy) + dz*dz)  (rn ops, no fma), mind = fminf(mind,d),
//   argmax = first occurrence of max (smallest index on exact float ties).
// Per step: minimal inner loop (fminf+fmaxf, no index carry); wave max via
// DPP; readlane(63) broadcast; all-lane kk recovery (static unroll); DPP
// u32-min over candidate n=(kk<<9)|tid for first-occurrence ties; lane 63
// writes (vbits, n) slot; scan 8 slots; single owner lane selects coords in
// a masked branch (other waves execz-skip) and broadcasts via LDS.
// Also computes pp[n] = |p|^2 (same rn order) for ball query.
// ---------------------------------------------------------------------------
__global__ __launch_bounds__(512) void k_fps(const float* __restrict__ xyz,
                                             float* __restrict__ pp,
                                             float* __restrict__ newxyz) {
  const int b = blockIdx.x, tid = threadIdx.x;
  const int wv = tid >> 6, lane = tid & 63;
  __shared__ uint2 slotVN[8];
  __shared__ float coordbuf[3];
  const float* Xb = xyz + (size_t)b * NPTS * 3;
  float px[16], py[16], pz[16], mind[16];
#pragma unroll
  for (int k = 0; k < 16; k++) {
    int n = (k << 9) | tid;
    float x = Xb[n*3+0], y = Xb[n*3+1], z = Xb[n*3+2];
    px[k]=x; py[k]=y; pz[k]=z;
    pp[b*NPTS + n] = __fadd_rn(__fadd_rn(__fmul_rn(x,x), __fmul_rn(y,y)), __fmul_rn(z,z));
    mind[k] = 1e10f;
  }
  if (tid == 0) {
    coordbuf[0]=px[0]; coordbuf[1]=py[0]; coordbuf[2]=pz[0];
    float* o = newxyz + (size_t)b*NS*3;
    o[0]=px[0]; o[1]=py[0]; o[2]=pz[0];
  }
  __syncthreads();
  float lx = coordbuf[0], ly = coordbuf[1], lz = coordbuf[2];
  for (int s = 1; s < NS; s++) {
    float v = -1.0f;
#pragma unroll
    for (int k = 0; k < 16; k++) {
      float dx = __fsub_rn(px[k], lx);
      float dy = __fsub_rn(py[k], ly);
      float dz = __fsub_rn(pz[k], lz);
      float d = __fadd_rn(__fadd_rn(__fmul_rn(dx,dx), __fmul_rn(dy,dy)), __fmul_rn(dz,dz));
      float m = fminf(mind[k], d);
      mind[k] = m;
      v = fmaxf(v, m);
    }
    // wave max (lane 63), broadcast to all lanes
    float vr = wave_max_f32(v);
    float wmax = __int_as_float(__builtin_amdgcn_readlane(__float_as_int(vr), 63));
    // first k with mind[k]==v (static unroll; only meaningful for candidates)
    int kk = 15;
#pragma unroll
    for (int k = 14; k >= 0; k--) kk = (mind[k] == v) ? k : kk;
    unsigned ncand = (v == wmax) ? (unsigned)((kk << 9) | tid) : 0xffffffffu;
    unsigned nr = wave_min_u32(ncand);
    if (lane == 63) slotVN[wv] = make_uint2(__float_as_uint(vr), nr);
    __syncthreads();   // barrier A: slots visible
    uint2 best = slotVN[0];
#pragma unroll
    for (int j = 1; j < 8; j++) {
      uint2 t = slotVN[j];
      if (t.x > best.x || (t.x == best.x && t.y < best.y)) best = t;
    }
    if (tid == (int)(best.y & 511u)) {   // unique owner lane in one wave
      int kk2 = (int)(best.y >> 9);
      float ox = px[kk2], oy = py[kk2], oz = pz[kk2];
      coordbuf[0] = ox; coordbuf[1] = oy; coordbuf[2] = oz;
      float* o = newxyz + ((size_t)b*NS + s)*3;
      o[0]=ox; o[1]=oy; o[2]=oz;
    }
    __syncthreads();   // barrier B: coords visible
    lx = coordbuf[0]; ly = coordbuf[1]; lz = coordbuf[2];
  }
}

// ---------------------------------------------------------------------------
// Ball query: one wave per centroid. Exact np-f32 expanded distance:
//   d2 = (qq + pp) - 2*((cx*x + cy*y) + cz*z), inside iff d2 <= 0.0625f.
// First NK in-index-order indices; pad with first found.
// ---------------------------------------------------------------------------
__global__ __launch_bounds__(256) void k_bq(const float* __restrict__ xyz,
                                            const float* __restrict__ pp,
                                            const float* __restrict__ newxyz,
                                            int* __restrict__ idx) {
  int wv = (blockIdx.x << 2) | (threadIdx.x >> 6);   // 0..16383
  int lane = threadIdx.x & 63;
  int b = wv >> 11;
  const float* c3 = newxyz + (size_t)wv * 3;
  float cx = c3[0], cy = c3[1], cz = c3[2];
  float qq = __fadd_rn(__fadd_rn(__fmul_rn(cx,cx), __fmul_rn(cy,cy)), __fmul_rn(cz,cz));
  const float* Xb = xyz + (size_t)b * NPTS * 3;
  const float* Pb = pp + b * NPTS;
  int* out = idx + (size_t)wv * NK;
  int cnt = 0, first = 0;
  for (int j0 = 0; j0 < NPTS; j0 += 64) {
    int n = j0 + lane;
    float x = Xb[n*3+0], y = Xb[n*3+1], z = Xb[n*3+2];
    float dot = __fadd_rn(__fadd_rn(__fmul_rn(cx,x), __fmul_rn(cy,y)), __fmul_rn(cz,z));
    float d2 = __fsub_rn(__fadd_rn(qq, Pb[n]), __fmul_rn(2.0f, dot));
    bool in = (d2 <= 0.0625f);
    unsigned long long bal = __ballot(in);
    if (cnt == 0 && bal) first = j0 + (int)__builtin_ctzll(bal);
    int c = (int)__popcll(bal);
    if (in) {
      int pos = cnt + (int)__popcll(bal & ((1ull << lane) - 1ull));
      if (pos < NK) out[pos] = n;
    }
    cnt += c;
    if (cnt >= NK) break;
  }
  if (cnt < NK) {
    if (lane >= cnt && lane < NK) out[lane] = first;
  }
}

// ---------------------------------------------------------------------------
// Gather helper: builds feat[j][r] tile (j = channel 0..66, r = row 0..31)
// in LDS for group gid. feat[0..2][r] = xyz[idx]-center; feat[3+c][r]=points.
// ---------------------------------------------------------------------------
#define GATHER_GROUP(gid_, b_)                                                   \
  do {                                                                           \
    if (tid < 32) s_idx[tid] = idx[(size_t)(gid_)*NK + tid];                     \
    if (tid < 3)  s_c[tid]   = newxyz[(size_t)(gid_)*3 + tid];                   \
    __syncthreads();                                                             \
    if (tid < 32) {                                                              \
      const float* p = &xyz[((size_t)(b_)*NPTS + s_idx[tid])*3];                 \
      feat[0*32+tid] = p[0] - s_c[0];                                            \
      feat[1*32+tid] = p[1] - s_c[1];                                            \
      feat[2*32+tid] = p[2] - s_c[2];                                            \
    }                                                                            \
    {                                                                            \
      int r_ = tid & 31, cq_ = tid >> 5;                                         \
      const float* pr = &pts[((size_t)(b_)*NPTS + s_idx[r_])*64 + cq_*8];        \
      float4 A_ = *(const float4*)pr;                                            \
      float4 B_ = *(const float4*)(pr + 4);                                      \
      feat[(3+cq_*8+0)*32 + r_] = A_.x;                                          \
      feat[(3+cq_*8+1)*32 + r_] = A_.y;                                          \
      feat[(3+cq_*8+2)*32 + r_] = A_.z;                                          \
      feat[(3+cq_*8+3)*32 + r_] = A_.w;                                          \
      feat[(3+cq_*8+4)*32 + r_] = B_.x;                                          \
      feat[(3+cq_*8+5)*32 + r_] = B_.y;                                          \
      feat[(3+cq_*8+6)*32 + r_] = B_.z;                                          \
      feat[(3+cq_*8+7)*32 + r_] = B_.w;                                          \
    }                                                                            \
    __syncthreads();                                                             \
  } while (0)

// ---------------------------------------------------------------------------
// Pass A: layer-0 GEMM (discard values), accumulate per-channel sum/sumsq.
// grid 512 x 256thr, 32 groups/block. ALL 256 threads: 4 rows x 2 cols.
// ---------------------------------------------------------------------------
__global__ __launch_bounds__(256) void k_l0stats(const float* __restrict__ xyz,
                                                 const float* __restrict__ pts,
                                                 const float* __restrict__ newxyz,
                                                 const int* __restrict__ idx,
                                                 const float* __restrict__ w0,
                                                 float* __restrict__ partials) {
  __shared__ __align__(16) float w0t[C0*64];
  __shared__ __align__(16) float feat[C0*32];
  __shared__ int s_idx[32];
  __shared__ float s_c[3];
  int tid = threadIdx.x;
  for (int t = tid; t < C0*64; t += 256) { int j = t >> 6, c = t & 63; w0t[t] = w0[c*C0 + j]; }
  int rt = tid & 7, ct = tid >> 3;          // rows rt*4.., cols ct*2..
  float s0[2] = {0,0}, q0[2] = {0,0};
  for (int g = 0; g < 32; g++) {
    int gid = blockIdx.x * 32 + g;
    int b = gid >> 11;
    __syncthreads();
    GATHER_GROUP(gid, b);
    float acc[4][2] = {};
    for (int j = 0; j < C0; j++) {
      float4 av = *(const float4*)&feat[j*32 + rt*4];
      float2 wv = *(const float2*)&w0t[j*64 + ct*2];
      float aa[4] = {av.x, av.y, av.z, av.w};
#pragma unroll
      for (int r = 0; r < 4; r++) {
        acc[r][0] = fmaf(aa[r], wv.x, acc[r][0]);
        acc[r][1] = fmaf(aa[r], wv.y, acc[r][1]);
      }
    }
#pragma unroll
    for (int r = 0; r < 4; r++)
#pragma unroll
      for (int u = 0; u < 2; u++) { float x = acc[r][u]; s0[u] += x; q0[u] = fmaf(x, x, q0[u]); }
  }
#pragma unroll
  for (int off = 1; off < 8; off <<= 1) {
#pragma unroll
    for (int u = 0; u < 2; u++) { s0[u] += __shfl_xor(s0[u], off, 64); q0[u] += __shfl_xor(q0[u], off, 64); }
  }
  if (rt == 0) {
#pragma unroll
    for (int u = 0; u < 2; u++) {
      size_t o = ((size_t)blockIdx.x * 128 + ct*2 + u) * 2;
      partials[o] = s0[u]; partials[o+1] = q0[u];
    }
  }
}

// ---------------------------------------------------------------------------
// Pass B: recompute L0, apply BN0+ReLU, L1 GEMM, accumulate stats1.
// ALL 256 threads: 4 rows x 2 cols per stage.
// ---------------------------------------------------------------------------
__global__ __launch_bounds__(256) void k_l1stats(const float* __restrict__ xyz,
                                                 const float* __restrict__ pts,
                                                 const float* __restrict__ newxyz,
                                                 const int* __restrict__ idx,
                                                 const float* __restrict__ w0,
                                                 const float* __restrict__ w1,
                                                 const float* __restrict__ statsF,
                                                 float* __restrict__ partials) {
  __shared__ __align__(16) float w0t[C0*64];
  __shared__ __align__(16) float w1t[64*64];
  __shared__ __align__(16) float feat[C0*32];
  __shared__ __align__(16) float x0n[64*32];
  __shared__ int s_idx[32];
  __shared__ float s_c[3];
  int tid = threadIdx.x;
  for (int t = tid; t < C0*64; t += 256) { int j = t >> 6, c = t & 63; w0t[t] = w0[c*C0 + j]; }
  for (int t = tid; t < 64*64; t += 256) { int j = t >> 6, c = t & 63; w1t[t] = w1[c*64 + j]; }
  int rt = tid & 7, ct = tid >> 3;
  float a0[2], b0v[2];
#pragma unroll
  for (int u = 0; u < 2; u++) {
    a0[u]  = statsF[(0*128 + ct*2 + u)*2];
    b0v[u] = statsF[(0*128 + ct*2 + u)*2 + 1];
  }
  float s1[2] = {0,0}, q1[2] = {0,0};
  for (int g = 0; g < 32; g++) {
    int gid = blockIdx.x * 32 + g;
    int b = gid >> 11;
    __syncthreads();
    GATHER_GROUP(gid, b);
    {
      float acc[4][2] = {};
      for (int j = 0; j < C0; j++) {
        float4 av = *(const float4*)&feat[j*32 + rt*4];
        float2 wv = *(const float2*)&w0t[j*64 + ct*2];
        float aa[4] = {av.x, av.y, av.z, av.w};
#pragma unroll
        for (int r = 0; r < 4; r++) {
          acc[r][0] = fmaf(aa[r], wv.x, acc[r][0]);
          acc[r][1] = fmaf(aa[r], wv.y, acc[r][1]);
        }
      }
#pragma unroll
      for (int u = 0; u < 2; u++) {
        float4 st;
        st.x = fmaxf(0.f, fmaf(acc[0][u], a0[u], b0v[u]));
        st.y = fmaxf(0.f, fmaf(acc[1][u], a0[u], b0v[u]));
        st.z = fmaxf(0.f, fmaf(acc[2][u], a0[u], b0v[u]));
        st.w = fmaxf(0.f, fmaf(acc[3][u], a0[u], b0v[u]));
        *(float4*)&x0n[(ct*2 + u)*32 + rt*4] = st;
      }
    }
    __syncthreads();
    {
      float acc[4][2] = {};
      for (int j = 0; j < 64; j++) {
        float4 av = *(const float4*)&x0n[j*32 + rt*4];
        float2 wv = *(const float2*)&w1t[j*64 + ct*2];
        float aa[4] = {av.x, av.y, av.z, av.w};
#pragma unroll
        for (int r = 0; r < 4; r++) {
          acc[r][0] = fmaf(aa[r], wv.x, acc[r][0]);
          acc[r][1] = fmaf(aa[r], wv.y, acc[r][1]);
        }
      }
#pragma unroll
      for (int r = 0; r < 4; r++)
#pragma unroll
        for (int u = 0; u < 2; u++) { float x = acc[r][u]; s1[u] += x; q1[u] = fmaf(x, x, q1[u]); }
    }
  }
#pragma unroll
  for (int off = 1; off < 8; off <<= 1) {
#pragma unroll
    for (int u = 0; u < 2; u++) { s1[u] += __shfl_xor(s1[u], off, 64); q1[u] += __shfl_xor(q1[u], off, 64); }
  }
  if (rt == 0) {
#pragma unroll
    for (int u = 0; u < 2; u++) {
      size_t o = ((size_t)blockIdx.x * 128 + ct*2 + u) * 2;
      partials[o] = s1[u]; partials[o+1] = q1[u];
    }
  }
}

// ---------------------------------------------------------------------------
// Pass C: recompute L0(BN0,ReLU), L1(BN1,ReLU), compute L2 pre-BN values:
// accumulate stats2 and per-(group,channel) max/min over the 32 rows.
// grid 256 x 256thr, 64 groups/block. ALL 256 threads active.
// ---------------------------------------------------------------------------
__global__ __launch_bounds__(256) void k_l2(const float* __restrict__ xyz,
                                            const float* __restrict__ pts,
                                            const float* __restrict__ newxyz,
                                            const int* __restrict__ idx,
                                            const float* __restrict__ w0,
                                            const float* __restrict__ w1,
                                            const float* __restrict__ w2,
                                            const float* __restrict__ statsF,
                                            float* __restrict__ partials,
                                            float* __restrict__ maxb,
                                            float* __restrict__ minb) {
  __shared__ __align__(16) float w0t[C0*64];
  __shared__ __align__(16) float w1t[64*64];
  __shared__ __align__(16) float w2t[64*128];
  __shared__ __align__(16) float feat[C0*32];
  __shared__ __align__(16) float x0n[64*32];
  __shared__ __align__(16) float x1n[64*32];
  __shared__ int s_idx[32];
  __shared__ float s_c[3];
  int tid = threadIdx.x;
  for (int t = tid; t < C0*64; t += 256) { int j = t >> 6, c = t & 63; w0t[t] = w0[c*C0 + j]; }
  for (int t = tid; t < 64*64; t += 256) { int j = t >> 6, c = t & 63; w1t[t] = w1[c*64 + j]; }
  for (int t = tid; t < 64*128; t += 256) { int j = t >> 7, c = t & 127; w2t[t] = w2[c*64 + j]; }
  int rt = tid & 7, ct = tid >> 3;   // rows rt*4.., L0/L1 cols ct*2.., L2 cols ct*4..
  float a0[2], b0v[2], a1[2], b1v[2];
#pragma unroll
  for (int u = 0; u < 2; u++) {
    a0[u]  = statsF[(0*128 + ct*2 + u)*2];
    b0v[u] = statsF[(0*128 + ct*2 + u)*2 + 1];
    a1[u]  = statsF[(1*128 + ct*2 + u)*2];
    b1v[u] = statsF[(1*128 + ct*2 + u)*2 + 1];
  }
  float s2[4] = {0,0,0,0}, q2[4] = {0,0,0,0};
  for (int g = 0; g < 64; g++) {
    int gid = blockIdx.x * 64 + g;
    int b = gid >> 11;
    __syncthreads();
    GATHER_GROUP(gid, b);
    {
      float acc[4][2] = {};
      for (int j = 0; j < C0; j++) {
        float4 av = *(const float4*)&feat[j*32 + rt*4];
        float2 wv = *(const float2*)&w0t[j*64 + ct*2];
        float aa[4] = {av.x, av.y, av.z, av.w};
#pragma unroll
        for (int r = 0; r < 4; r++) {
          acc[r][0] = fmaf(aa[r], wv.x, acc[r][0]);
          acc[r][1] = fmaf(aa[r], wv.y, acc[r][1]);
        }
      }
#pragma unroll
      for (int u = 0; u < 2; u++) {
        float4 st;
        st.x = fmaxf(0.f, fmaf(acc[0][u], a0[u], b0v[u]));
        st.y = fmaxf(0.f, fmaf(acc[1][u], a0[u], b0v[u]));
        st.z = fmaxf(0.f, fmaf(acc[2][u], a0[u], b0v[u]));
        st.w = fmaxf(0.f, fmaf(acc[3][u], a0[u], b0v[u]));
        *(float4*)&x0n[(ct*2 + u)*32 + rt*4] = st;
      }
    }
    __syncthreads();
    {
      float acc[4][2] = {};
      for (int j = 0; j < 64; j++) {
        float4 av = *(const float4*)&x0n[j*32 + rt*4];
        float2 wv = *(const float2*)&w1t[j*64 + ct*2];
        float aa[4] = {av.x, av.y, av.z, av.w};
#pragma unroll
        for (int r = 0; r < 4; r++) {
          acc[r][0] = fmaf(aa[r], wv.x, acc[r][0]);
          acc[r][1] = fmaf(aa[r], wv.y, acc[r][1]);
        }
      }
#pragma unroll
      for (int u = 0; u < 2; u++) {
        float4 st;
        st.x = fmaxf(0.f, fmaf(acc[0][u], a1[u], b1v[u]));
        st.y = fmaxf(0.f, fmaf(acc[1][u], a1[u], b1v[u]));
        st.z = fmaxf(0.f, fmaf(acc[2][u], a1[u], b1v[u]));
        st.w = fmaxf(0.f, fmaf(acc[3][u], a1[u], b1v[u]));
        *(float4*)&x1n[(ct*2 + u)*32 + rt*4] = st;
      }
    }
    __syncthreads();
    {  // L2: 4 rows x 4 cols per thread, cols ct*4..ct*4+3
      float acc[4][4] = {};
      for (int j = 0; j < 64; j++) {
        float4 av = *(const float4*)&x1n[j*32 + rt*4];
        float4 wvv = *(const float4*)&w2t[j*128 + ct*4];
        float aa[4] = {av.x, av.y, av.z, av.w};
        float ww[4] = {wvv.x, wvv.y, wvv.z, wvv.w};
#pragma unroll
        for (int r = 0; r < 4; r++)
#pragma unroll
          for (int u = 0; u < 4; u++) acc[r][u] = fmaf(aa[r], ww[u], acc[r][u]);
      }
      float mx[4], mn[4];
#pragma unroll
      for (int u = 0; u < 4; u++) {
        float x0 = acc[0][u], x1 = acc[1][u], x2 = acc[2][u], x3 = acc[3][u];
        s2[u] += ((x0 + x1) + (x2 + x3));
        q2[u] = fmaf(x0, x0, q2[u]); q2[u] = fmaf(x1, x1, q2[u]);
        q2[u] = fmaf(x2, x2, q2[u]); q2[u] = fmaf(x3, x3, q2[u]);
        mx[u] = fmaxf(fmaxf(x0, x1), fmaxf(x2, x3));
        mn[u] = fminf(fminf(x0, x1), fminf(x2, x3));
      }
#pragma unroll
      for (int off = 1; off < 8; off <<= 1) {
#pragma unroll
        for (int u = 0; u < 4; u++) {
          mx[u] = fmaxf(mx[u], __shfl_xor(mx[u], off, 64));
          mn[u] = fminf(mn[u], __shfl_xor(mn[u], off, 64));
        }
      }
      if (rt == 0) {
#pragma unroll
        for (int u = 0; u < 4; u++) {
          maxb[(size_t)gid*128 + ct*4 + u] = mx[u];
          minb[(size_t)gid*128 + ct*4 + u] = mn[u];
        }
      }
    }
  }
#pragma unroll
  for (int off = 1; off < 8; off <<= 1) {
#pragma unroll
    for (int u = 0; u < 4; u++) { s2[u] += __shfl_xor(s2[u], off, 64); q2[u] += __shfl_xor(q2[u], off, 64); }
  }
  if (rt == 0) {
#pragma unroll
    for (int u = 0; u < 4; u++) {
      size_t o = ((size_t)blockIdx.x * 128 + ct*4 + u) * 2;
      partials[o] = s2[u]; partials[o+1] = q2[u];
    }
  }
}

// ---------------------------------------------------------------------------
// Finalize BN stats: reduce per-block partials -> a = g/sqrt(var+eps),
// beta = be - mean*a. One block, C threads.
// ---------------------------------------------------------------------------
__global__ void k_fin(const float* __restrict__ partials, int nblk,
                      const float* __restrict__ g, const float* __restrict__ be,
                      float* __restrict__ statsF, int layer, int C) {
  int c = threadIdx.x;
  if (c >= C) return;
  float s = 0.f, q = 0.f;
  for (int k = 0; k < nblk; k++) {
    s += partials[((size_t)k * 128 + c) * 2];
    q += partials[((size_t)k * 128 + c) * 2 + 1];
  }
  const float inv = 1.0f / (float)NTOT;
  float mean = s * inv;
  float var = q * inv - mean * mean;
  float a = g[c] / sqrtf(var + 1e-5f);
  float bb = be[c] - mean * a;
  statsF[((size_t)layer * 128 + c) * 2]     = a;
  statsF[((size_t)layer * 128 + c) * 2 + 1] = bb;
}

// ---------------------------------------------------------------------------
// Pooling epilogue: pooled = relu(a*X + beta), X = (a>=0 ? max : min).
// (BN affine is monotone; relu is monotone -> maxpool commutes.)
// ---------------------------------------------------------------------------
__global__ __launch_bounds__(256) void k_pool(const float* __restrict__ maxb,
                                              const float* __restrict__ minb,
                                              const float* __restrict__ statsF,
                                              float* __restrict__ outp) {
  int t = blockIdx.x * 256 + threadIdx.x;   // < 16384*128
  int c = t & 127;
  float a  = statsF[(2*128 + c)*2];
  float bb = statsF[(2*128 + c)*2 + 1];
  float X = (a >= 0.f) ? maxb[t] : minb[t];
  outp[t] = fmaxf(0.f, fmaf(a, X, bb));
}

// ---------------------------------------------------------------------------
extern "C" void kernel_launch(void* const* d_in, const int* in_sizes, int n_in,
                              void* d_out, int out_size, void* d_ws, size_t ws_size,
                              hipStream_t stream) {
  (void)in_sizes; (void)n_in; (void)out_size; (void)ws_size;
  const float* xyz = (const float*)d_in[0];
  const float* pts = (const float*)d_in[1];
  const float* w0  = (const float*)d_in[2];
  const float* g0  = (const float*)d_in[4];
  const float* be0 = (const float*)d_in[5];
  const float* w1  = (const float*)d_in[6];
  const float* g1  = (const float*)d_in[8];
  const float* be1 = (const float*)d_in[9];
  const float* w2  = (const float*)d_in[10];
  const float* g2  = (const float*)d_in[12];
  const float* be2 = (const float*)d_in[13];

  float* out = (float*)d_out;
  float* newxyz = out;                    // [B,S,3]
  float* pooled = out + (size_t)NB*NS*3;  // [B,S,128]

  float* ws = (float*)d_ws;
  float* pp     = ws;                                 // 65536
  int*   idx    = (int*)(ws + 65536);                 // 524288 ints
  float* part   = ws + 65536 + 524288;                // 512*128*2 = 131072
  float* statsF = part + 131072;                      // 768
  float* maxb   = statsF + 768;                       // 2097152
  float* minb   = maxb + 2097152;                     // 2097152

  k_fps<<<NB, 512, 0, stream>>>(xyz, pp, newxyz);
  k_bq<<<4096, 256, 0, stream>>>(xyz, pp, newxyz, idx);
  k_l0stats<<<512, 256, 0, stream>>>(xyz, pts, newxyz, idx, w0, part);
  k_fin<<<1, 128, 0, stream>>>(part, 512, g0, be0, statsF, 0, 64);
  k_l1stats<<<512, 256, 0, stream>>>(xyz, pts, newxyz, idx, w0, w1, statsF, part);
  k_fin<<<1, 128, 0, stream>>>(part, 512, g1, be1, statsF, 1, 64);
  k_l2<<<256, 256, 0, stream>>>(xyz, pts, newxyz, idx, w0, w1, w2, statsF, part, maxb, minb);
  k_fin<<<1, 128, 0, stream>>>(part, 256, g2, be2, statsF, 2, 128);
  k_pool<<<8192, 256, 0, stream>>>(maxb, minb, statsF, pooled);
}

// Round 5
// 3618.031 us; speedup vs baseline: 1.3648x; 1.1436x over previous
//
#include <hip/hip_runtime.h>

#define NPTS 8192
#define NB 8
#define NS 2048
#define NK 32
// channel sizes
#define C0 67
#define C1 64
#define C2 64
#define C3 128
#define NTOT (NB*NS*NK)   // 524288 rows

// ---- DPP wave64 reduce helpers (VALU-speed cross-lane; result in lane 63) --
template <int CTRL, int ROWM>
__device__ __forceinline__ float dpp_fmax_step(float x) {
  int yi = __builtin_amdgcn_update_dpp(__float_as_int(x), __float_as_int(x),
                                       CTRL, ROWM, 0xf, false);
  return fmaxf(x, __int_as_float(yi));
}
template <int CTRL, int ROWM>
__device__ __forceinline__ unsigned dpp_umin_step(unsigned x) {
  unsigned y = (unsigned)__builtin_amdgcn_update_dpp((int)x, (int)x,
                                                     CTRL, ROWM, 0xf, false);
  return (y < x) ? y : x;
}
__device__ __forceinline__ float wave_max_f32(float v) {
  v = dpp_fmax_step<0x111, 0xf>(v);  // row_shr:1
  v = dpp_fmax_step<0x112, 0xf>(v);  // row_shr:2
  v = dpp_fmax_step<0x114, 0xf>(v);  // row_shr:4
  v = dpp_fmax_step<0x118, 0xf>(v);  // row_shr:8
  v = dpp_fmax_step<0x142, 0xa>(v);  // row_bcast:15 -> rows 1,3
  v = dpp_fmax_step<0x143, 0xc>(v);  // row_bcast:31 -> rows 2,3
  return v;                           // lane 63 = wave max
}
__device__ __forceinline__ unsigned wave_min_u32(unsigned v) {
  v = dpp_umin_step<0x111, 0xf>(v);
  v = dpp_umin_step<0x112, 0xf>(v);
  v = dpp_umin_step<0x114, 0xf>(v);
  v = dpp_umin_step<0x118, 0xf>(v);
  v = dpp_umin_step<0x142, 0xa>(v);
  v = dpp_umin_step<0x143, 0xc>(v);
  return v;                           // lane 63 = wave min
}

// ---------------------------------------------------------------------------
// FPS: one block (256 thr = 4 waves, 1 wave/SIMD) per batch. Exact np-f32:
//   d = ((dx*dx + dy*dy) + dz*dz)  (rn ops, no fma), mind = fminf(mind,d),
//   argmax = first occurrence of max (smallest linear index on exact ties).
// Structure: 32 pts/thread in registers; LDS coord mirror sx/sy/sz (written
// once at init) so after ONE barrier every thread resolves the winner's
// coords itself (broadcast LDS read) -- no owner-write round trip, no 2nd
// barrier. Slots double-buffered by s&1 for race-free reuse.
// Also computes pp[n] = |p|^2 (same rn order) for ball query.
// ---------------------------------------------------------------------------
__global__ __launch_bounds__(256) void k_fps(const float* __restrict__ xyz,
                                             float* __restrict__ pp,
                                             float* __restrict__ newxyz) {
  const int b = blockIdx.x, tid = threadIdx.x;
  const int wv = tid >> 6, lane = tid & 63;
  __shared__ float sx[NPTS], sy[NPTS], sz[NPTS];
  __shared__ uint2 slotVN[2][4];
  const float* Xb = xyz + (size_t)b * NPTS * 3;
  float px[32], py[32], pz[32], mind[32];
#pragma unroll
  for (int k = 0; k < 32; k++) {
    int n = (k << 8) | tid;
    float x = Xb[n*3+0], y = Xb[n*3+1], z = Xb[n*3+2];
    px[k]=x; py[k]=y; pz[k]=z;
    sx[n]=x; sy[n]=y; sz[n]=z;
    pp[b*NPTS + n] = __fadd_rn(__fadd_rn(__fmul_rn(x,x), __fmul_rn(y,y)), __fmul_rn(z,z));
    mind[k] = 1e10f;
  }
  __syncthreads();
  float lx = sx[0], ly = sy[0], lz = sz[0];
  if (tid == 0) {
    float* o = newxyz + (size_t)b*NS*3;
    o[0]=lx; o[1]=ly; o[2]=lz;
  }
  for (int s = 1; s < NS; s++) {
    float v = -1.0f;
#pragma unroll
    for (int k = 0; k < 32; k++) {
      float dx = __fsub_rn(px[k], lx);
      float dy = __fsub_rn(py[k], ly);
      float dz = __fsub_rn(pz[k], lz);
      float d = __fadd_rn(__fadd_rn(__fmul_rn(dx,dx), __fmul_rn(dy,dy)), __fmul_rn(dz,dz));
      float m = fminf(mind[k], d);
      mind[k] = m;
      v = fmaxf(v, m);
    }
    // wave max (lane 63), broadcast to all lanes
    float vr = wave_max_f32(v);
    float wmax = __int_as_float(__builtin_amdgcn_readlane(__float_as_int(vr), 63));
    // first k with mind[k]==v (static unroll; meaningful only for candidates)
    int kk = 31;
#pragma unroll
    for (int k = 30; k >= 0; k--) kk = (mind[k] == v) ? k : kk;
    unsigned ncand = (v == wmax) ? (unsigned)((kk << 8) | tid) : 0xffffffffu;
    unsigned nr = wave_min_u32(ncand);
    int buf = s & 1;
    if (lane == 63) slotVN[buf][wv] = make_uint2(__float_as_uint(vr), nr);
    __syncthreads();   // single barrier per step
    uint2 best = slotVN[buf][0];
#pragma unroll
    for (int j = 1; j < 4; j++) {
      uint2 t = slotVN[buf][j];
      bool gt = (t.x > best.x) || (t.x == best.x && t.y < best.y);
      if (gt) best = t;
    }
    int n = (int)best.y;
    lx = sx[n]; ly = sy[n]; lz = sz[n];   // broadcast reads, conflict-free
    if (tid == 0) {
      float* o = newxyz + ((size_t)b*NS + s)*3;
      o[0]=lx; o[1]=ly; o[2]=lz;
    }
  }
}

// ---------------------------------------------------------------------------
// Ball query: one wave per centroid. Exact np-f32 expanded distance:
//   d2 = (qq + pp) - 2*((cx*x + cy*y) + cz*z), inside iff d2 <= 0.0625f.
// First NK in-index-order indices; pad with first found.
// ---------------------------------------------------------------------------
__global__ __launch_bounds__(256) void k_bq(const float* __restrict__ xyz,
                                            const float* __restrict__ pp,
                                            const float* __restrict__ newxyz,
                                            int* __restrict__ idx) {
  int wv = (blockIdx.x << 2) | (threadIdx.x >> 6);   // 0..16383
  int lane = threadIdx.x & 63;
  int b = wv >> 11;
  const float* c3 = newxyz + (size_t)wv * 3;
  float cx = c3[0], cy = c3[1], cz = c3[2];
  float qq = __fadd_rn(__fadd_rn(__fmul_rn(cx,cx), __fmul_rn(cy,cy)), __fmul_rn(cz,cz));
  const float* Xb = xyz + (size_t)b * NPTS * 3;
  const float* Pb = pp + b * NPTS;
  int* out = idx + (size_t)wv * NK;
  int cnt = 0, first = 0;
  for (int j0 = 0; j0 < NPTS; j0 += 64) {
    int n = j0 + lane;
    float x = Xb[n*3+0], y = Xb[n*3+1], z = Xb[n*3+2];
    float dot = __fadd_rn(__fadd_rn(__fmul_rn(cx,x), __fmul_rn(cy,y)), __fmul_rn(cz,z));
    float d2 = __fsub_rn(__fadd_rn(qq, Pb[n]), __fmul_rn(2.0f, dot));
    bool in = (d2 <= 0.0625f);
    unsigned long long bal = __ballot(in);
    if (cnt == 0 && bal) first = j0 + (int)__builtin_ctzll(bal);
    int c = (int)__popcll(bal);
    if (in) {
      int pos = cnt + (int)__popcll(bal & ((1ull << lane) - 1ull));
      if (pos < NK) out[pos] = n;
    }
    cnt += c;
    if (cnt >= NK) break;
  }
  if (cnt < NK) {
    if (lane >= cnt && lane < NK) out[lane] = first;
  }
}

// ---------------------------------------------------------------------------
// Gather helper: builds feat[j][r] tile (j = channel 0..66, r = row 0..31)
// in LDS for group gid. feat[0..2][r] = xyz[idx]-center; feat[3+c][r]=points.
// ---------------------------------------------------------------------------
#define GATHER_GROUP(gid_, b_)                                                   \
  do {                                                                           \
    if (tid < 32) s_idx[tid] = idx[(size_t)(gid_)*NK + tid];                     \
    if (tid < 3)  s_c[tid]   = newxyz[(size_t)(gid_)*3 + tid];                   \
    __syncthreads();                                                             \
    if (tid < 32) {                                                              \
      const float* p = &xyz[((size_t)(b_)*NPTS + s_idx[tid])*3];                 \
      feat[0*32+tid] = p[0] - s_c[0];                                            \
      feat[1*32+tid] = p[1] - s_c[1];                                            \
      feat[2*32+tid] = p[2] - s_c[2];                                            \
    }                                                                            \
    {                                                                            \
      int r_ = tid & 31, cq_ = tid >> 5;                                         \
      const float* pr = &pts[((size_t)(b_)*NPTS + s_idx[r_])*64 + cq_*8];        \
      float4 A_ = *(const float4*)pr;                                            \
      float4 B_ = *(const float4*)(pr + 4);                                      \
      feat[(3+cq_*8+0)*32 + r_] = A_.x;                                          \
      feat[(3+cq_*8+1)*32 + r_] = A_.y;                                          \
      feat[(3+cq_*8+2)*32 + r_] = A_.z;                                          \
      feat[(3+cq_*8+3)*32 + r_] = A_.w;                                          \
      feat[(3+cq_*8+4)*32 + r_] = B_.x;                                          \
      feat[(3+cq_*8+5)*32 + r_] = B_.y;                                          \
      feat[(3+cq_*8+6)*32 + r_] = B_.z;                                          \
      feat[(3+cq_*8+7)*32 + r_] = B_.w;                                          \
    }                                                                            \
    __syncthreads();                                                             \
  } while (0)

// ---------------------------------------------------------------------------
// Pass A: layer-0 GEMM (discard values), accumulate per-channel sum/sumsq.
// grid 512 x 256thr, 32 groups/block. ALL 256 threads: 4 rows x 2 cols.
// ---------------------------------------------------------------------------
__global__ __launch_bounds__(256) void k_l0stats(const float* __restrict__ xyz,
                                                 const float* __restrict__ pts,
                                                 const float* __restrict__ newxyz,
                                                 const int* __restrict__ idx,
                                                 const float* __restrict__ w0,
                                                 float* __restrict__ partials) {
  __shared__ __align__(16) float w0t[C0*64];
  __shared__ __align__(16) float feat[C0*32];
  __shared__ int s_idx[32];
  __shared__ float s_c[3];
  int tid = threadIdx.x;
  for (int t = tid; t < C0*64; t += 256) { int j = t >> 6, c = t & 63; w0t[t] = w0[c*C0 + j]; }
  int rt = tid & 7, ct = tid >> 3;          // rows rt*4.., cols ct*2..
  float s0[2] = {0,0}, q0[2] = {0,0};
  for (int g = 0; g < 32; g++) {
    int gid = blockIdx.x * 32 + g;
    int b = gid >> 11;
    __syncthreads();
    GATHER_GROUP(gid, b);
    float acc[4][2] = {};
    for (int j = 0; j < C0; j++) {
      float4 av = *(const float4*)&feat[j*32 + rt*4];
      float2 wv = *(const float2*)&w0t[j*64 + ct*2];
      float aa[4] = {av.x, av.y, av.z, av.w};
#pragma unroll
      for (int r = 0; r < 4; r++) {
        acc[r][0] = fmaf(aa[r], wv.x, acc[r][0]);
        acc[r][1] = fmaf(aa[r], wv.y, acc[r][1]);
      }
    }
#pragma unroll
    for (int r = 0; r < 4; r++)
#pragma unroll
      for (int u = 0; u < 2; u++) { float x = acc[r][u]; s0[u] += x; q0[u] = fmaf(x, x, q0[u]); }
  }
#pragma unroll
  for (int off = 1; off < 8; off <<= 1) {
#pragma unroll
    for (int u = 0; u < 2; u++) { s0[u] += __shfl_xor(s0[u], off, 64); q0[u] += __shfl_xor(q0[u], off, 64); }
  }
  if (rt == 0) {
#pragma unroll
    for (int u = 0; u < 2; u++) {
      size_t o = ((size_t)blockIdx.x * 128 + ct*2 + u) * 2;
      partials[o] = s0[u]; partials[o+1] = q0[u];
    }
  }
}

// ---------------------------------------------------------------------------
// Pass B: recompute L0, apply BN0+ReLU, L1 GEMM, accumulate stats1.
// ALL 256 threads: 4 rows x 2 cols per stage.
// ---------------------------------------------------------------------------
__global__ __launch_bounds__(256) void k_l1stats(const float* __restrict__ xyz,
                                                 const float* __restrict__ pts,
                                                 const float* __restrict__ newxyz,
                                                 const int* __restrict__ idx,
                                                 const float* __restrict__ w0,
                                                 const float* __restrict__ w1,
                                                 const float* __restrict__ statsF,
                                                 float* __restrict__ partials) {
  __shared__ __align__(16) float w0t[C0*64];
  __shared__ __align__(16) float w1t[64*64];
  __shared__ __align__(16) float feat[C0*32];
  __shared__ __align__(16) float x0n[64*32];
  __shared__ int s_idx[32];
  __shared__ float s_c[3];
  int tid = threadIdx.x;
  for (int t = tid; t < C0*64; t += 256) { int j = t >> 6, c = t & 63; w0t[t] = w0[c*C0 + j]; }
  for (int t = tid; t < 64*64; t += 256) { int j = t >> 6, c = t & 63; w1t[t] = w1[c*64 + j]; }
  int rt = tid & 7, ct = tid >> 3;
  float a0[2], b0v[2];
#pragma unroll
  for (int u = 0; u < 2; u++) {
    a0[u]  = statsF[(0*128 + ct*2 + u)*2];
    b0v[u] = statsF[(0*128 + ct*2 + u)*2 + 1];
  }
  float s1[2] = {0,0}, q1[2] = {0,0};
  for (int g = 0; g < 32; g++) {
    int gid = blockIdx.x * 32 + g;
    int b = gid >> 11;
    __syncthreads();
    GATHER_GROUP(gid, b);
    {
      float acc[4][2] = {};
      for (int j = 0; j < C0; j++) {
        float4 av = *(const float4*)&feat[j*32 + rt*4];
        float2 wv = *(const float2*)&w0t[j*64 + ct*2];
        float aa[4] = {av.x, av.y, av.z, av.w};
#pragma unroll
        for (int r = 0; r < 4; r++) {
          acc[r][0] = fmaf(aa[r], wv.x, acc[r][0]);
          acc[r][1] = fmaf(aa[r], wv.y, acc[r][1]);
        }
      }
#pragma unroll
      for (int u = 0; u < 2; u++) {
        float4 st;
        st.x = fmaxf(0.f, fmaf(acc[0][u], a0[u], b0v[u]));
        st.y = fmaxf(0.f, fmaf(acc[1][u], a0[u], b0v[u]));
        st.z = fmaxf(0.f, fmaf(acc[2][u], a0[u], b0v[u]));
        st.w = fmaxf(0.f, fmaf(acc[3][u], a0[u], b0v[u]));
        *(float4*)&x0n[(ct*2 + u)*32 + rt*4] = st;
      }
    }
    __syncthreads();
    {
      float acc[4][2] = {};
      for (int j = 0; j < 64; j++) {
        float4 av = *(const float4*)&x0n[j*32 + rt*4];
        float2 wv = *(const float2*)&w1t[j*64 + ct*2];
        float aa[4] = {av.x, av.y, av.z, av.w};
#pragma unroll
        for (int r = 0; r < 4; r++) {
          acc[r][0] = fmaf(aa[r], wv.x, acc[r][0]);
          acc[r][1] = fmaf(aa[r], wv.y, acc[r][1]);
        }
      }
#pragma unroll
      for (int r = 0; r < 4; r++)
#pragma unroll
        for (int u = 0; u < 2; u++) { float x = acc[r][u]; s1[u] += x; q1[u] = fmaf(x, x, q1[u]); }
    }
  }
#pragma unroll
  for (int off = 1; off < 8; off <<= 1) {
#pragma unroll
    for (int u = 0; u < 2; u++) { s1[u] += __shfl_xor(s1[u], off, 64); q1[u] += __shfl_xor(q1[u], off, 64); }
  }
  if (rt == 0) {
#pragma unroll
    for (int u = 0; u < 2; u++) {
      size_t o = ((size_t)blockIdx.x * 128 + ct*2 + u) * 2;
      partials[o] = s1[u]; partials[o+1] = q1[u];
    }
  }
}

// ---------------------------------------------------------------------------
// Pass C: recompute L0(BN0,ReLU), L1(BN1,ReLU), compute L2 pre-BN values:
// accumulate stats2 and per-(group,channel) max/min over the 32 rows.
// grid 256 x 256thr, 64 groups/block. ALL 256 threads active.
// ---------------------------------------------------------------------------
__global__ __launch_bounds__(256) void k_l2(const float* __restrict__ xyz,
                                            const float* __restrict__ pts,
                                            const float* __restrict__ newxyz,
                                            const int* __restrict__ idx,
                                            const float* __restrict__ w0,
                                            const float* __restrict__ w1,
                                            const float* __restrict__ w2,
                                            const float* __restrict__ statsF,
                                            float* __restrict__ partials,
                                            float* __restrict__ maxb,
                                            float* __restrict__ minb) {
  __shared__ __align__(16) float w0t[C0*64];
  __shared__ __align__(16) float w1t[64*64];
  __shared__ __align__(16) float w2t[64*128];
  __shared__ __align__(16) float feat[C0*32];
  __shared__ __align__(16) float x0n[64*32];
  __shared__ __align__(16) float x1n[64*32];
  __shared__ int s_idx[32];
  __shared__ float s_c[3];
  int tid = threadIdx.x;
  for (int t = tid; t < C0*64; t += 256) { int j = t >> 6, c = t & 63; w0t[t] = w0[c*C0 + j]; }
  for (int t = tid; t < 64*64; t += 256) { int j = t >> 6, c = t & 63; w1t[t] = w1[c*64 + j]; }
  for (int t = tid; t < 64*128; t += 256) { int j = t >> 7, c = t & 127; w2t[t] = w2[c*64 + j]; }
  int rt = tid & 7, ct = tid >> 3;   // rows rt*4.., L0/L1 cols ct*2.., L2 cols ct*4..
  float a0[2], b0v[2], a1[2], b1v[2];
#pragma unroll
  for (int u = 0; u < 2; u++) {
    a0[u]  = statsF[(0*128 + ct*2 + u)*2];
    b0v[u] = statsF[(0*128 + ct*2 + u)*2 + 1];
    a1[u]  = statsF[(1*128 + ct*2 + u)*2];
    b1v[u] = statsF[(1*128 + ct*2 + u)*2 + 1];
  }
  float s2[4] = {0,0,0,0}, q2[4] = {0,0,0,0};
  for (int g = 0; g < 64; g++) {
    int gid = blockIdx.x * 64 + g;
    int b = gid >> 11;
    __syncthreads();
    GATHER_GROUP(gid, b);
    {
      float acc[4][2] = {};
      for (int j = 0; j < C0; j++) {
        float4 av = *(const float4*)&feat[j*32 + rt*4];
        float2 wv = *(const float2*)&w0t[j*64 + ct*2];
        float aa[4] = {av.x, av.y, av.z, av.w};
#pragma unroll
        for (int r = 0; r < 4; r++) {
          acc[r][0] = fmaf(aa[r], wv.x, acc[r][0]);
          acc[r][1] = fmaf(aa[r], wv.y, acc[r][1]);
        }
      }
#pragma unroll
      for (int u = 0; u < 2; u++) {
        float4 st;
        st.x = fmaxf(0.f, fmaf(acc[0][u], a0[u], b0v[u]));
        st.y = fmaxf(0.f, fmaf(acc[1][u], a0[u], b0v[u]));
        st.z = fmaxf(0.f, fmaf(acc[2][u], a0[u], b0v[u]));
        st.w = fmaxf(0.f, fmaf(acc[3][u], a0[u], b0v[u]));
        *(float4*)&x0n[(ct*2 + u)*32 + rt*4] = st;
      }
    }
    __syncthreads();
    {
      float acc[4][2] = {};
      for (int j = 0; j < 64; j++) {
        float4 av = *(const float4*)&x0n[j*32 + rt*4];
        float2 wv = *(const float2*)&w1t[j*64 + ct*2];
        float aa[4] = {av.x, av.y, av.z, av.w};
#pragma unroll
        for (int r = 0; r < 4; r++) {
          acc[r][0] = fmaf(aa[r], wv.x, acc[r][0]);
          acc[r][1] = fmaf(aa[r], wv.y, acc[r][1]);
        }
      }
#pragma unroll
      for (int u = 0; u < 2; u++) {
        float4 st;
        st.x = fmaxf(0.f, fmaf(acc[0][u], a1[u], b1v[u]));
        st.y = fmaxf(0.f, fmaf(acc[1][u], a1[u], b1v[u]));
        st.z = fmaxf(0.f, fmaf(acc[2][u], a1[u], b1v[u]));
        st.w = fmaxf(0.f, fmaf(acc[3][u], a1[u], b1v[u]));
        *(float4*)&x1n[(ct*2 + u)*32 + rt*4] = st;
      }
    }
    __syncthreads();
    {  // L2: 4 rows x 4 cols per thread, cols ct*4..ct*4+3
      float acc[4][4] = {};
      for (int j = 0; j < 64; j++) {
        float4 av = *(const float4*)&x1n[j*32 + rt*4];
        float4 wvv = *(const float4*)&w2t[j*128 + ct*4];
        float aa[4] = {av.x, av.y, av.z, av.w};
        float ww[4] = {wvv.x, wvv.y, wvv.z, wvv.w};
#pragma unroll
        for (int r = 0; r < 4; r++)
#pragma unroll
          for (int u = 0; u < 4; u++) acc[r][u] = fmaf(aa[r], ww[u], acc[r][u]);
      }
      float mx[4], mn[4];
#pragma unroll
      for (int u = 0; u < 4; u++) {
        float x0 = acc[0][u], x1 = acc[1][u], x2 = acc[2][u], x3 = acc[3][u];
        s2[u] += ((x0 + x1) + (x2 + x3));
        q2[u] = fmaf(x0, x0, q2[u]); q2[u] = fmaf(x1, x1, q2[u]);
        q2[u] = fmaf(x2, x2, q2[u]); q2[u] = fmaf(x3, x3, q2[u]);
        mx[u] = fmaxf(fmaxf(x0, x1), fmaxf(x2, x3));
        mn[u] = fminf(fminf(x0, x1), fminf(x2, x3));
      }
#pragma unroll
      for (int off = 1; off < 8; off <<= 1) {
#pragma unroll
        for (int u = 0; u < 4; u++) {
          mx[u] = fmaxf(mx[u], __shfl_xor(mx[u], off, 64));
          mn[u] = fminf(mn[u], __shfl_xor(mn[u], off, 64));
        }
      }
      if (rt == 0) {
#pragma unroll
        for (int u = 0; u < 4; u++) {
          maxb[(size_t)gid*128 + ct*4 + u] = mx[u];
          minb[(size_t)gid*128 + ct*4 + u] = mn[u];
        }
      }
    }
  }
#pragma unroll
  for (int off = 1; off < 8; off <<= 1) {
#pragma unroll
    for (int u = 0; u < 4; u++) { s2[u] += __shfl_xor(s2[u], off, 64); q2[u] += __shfl_xor(q2[u], off, 64); }
  }
  if (rt == 0) {
#pragma unroll
    for (int u = 0; u < 4; u++) {
      size_t o = ((size_t)blockIdx.x * 128 + ct*4 + u) * 2;
      partials[o] = s2[u]; partials[o+1] = q2[u];
    }
  }
}

// ---------------------------------------------------------------------------
// Finalize BN stats: reduce per-block partials -> a = g/sqrt(var+eps),
// beta = be - mean*a. One block, C threads.
// ---------------------------------------------------------------------------
__global__ void k_fin(const float* __restrict__ partials, int nblk,
                      const float* __restrict__ g, const float* __restrict__ be,
                      float* __restrict__ statsF, int layer, int C) {
  int c = threadIdx.x;
  if (c >= C) return;
  float s = 0.f, q = 0.f;
  for (int k = 0; k < nblk; k++) {
    s += partials[((size_t)k * 128 + c) * 2];
    q += partials[((size_t)k * 128 + c) * 2 + 1];
  }
  const float inv = 1.0f / (float)NTOT;
  float mean = s * inv;
  float var = q * inv - mean * mean;
  float a = g[c] / sqrtf(var + 1e-5f);
  float bb = be[c] - mean * a;
  statsF[((size_t)layer * 128 + c) * 2]     = a;
  statsF[((size_t)layer * 128 + c) * 2 + 1] = bb;
}

// ---------------------------------------------------------------------------
// Pooling epilogue: pooled = relu(a*X + beta), X = (a>=0 ? max : min).
// (BN affine is monotone; relu is monotone -> maxpool commutes.)
// ---------------------------------------------------------------------------
__global__ __launch_bounds__(256) void k_pool(const float* __restrict__ maxb,
                                              const float* __restrict__ minb,
                                              const float* __restrict__ statsF,
                                              float* __restrict__ outp) {
  int t = blockIdx.x * 256 + threadIdx.x;   // < 16384*128
  int c = t & 127;
  float a  = statsF[(2*128 + c)*2];
  float bb = statsF[(2*128 + c)*2 + 1];
  float X = (a >= 0.f) ? maxb[t] : minb[t];
  outp[t] = fmaxf(0.f, fmaf(a, X, bb));
}

// ---------------------------------------------------------------------------
extern "C" void kernel_launch(void* const* d_in, const int* in_sizes, int n_in,
                              void* d_out, int out_size, void* d_ws, size_t ws_size,
                              hipStream_t stream) {
  (void)in_sizes; (void)n_in; (void)out_size; (void)ws_size;
  const float* xyz = (const float*)d_in[0];
  const float* pts = (const float*)d_in[1];
  const float* w0  = (const float*)d_in[2];
  const float* g0  = (const float*)d_in[4];
  const float* be0 = (const float*)d_in[5];
  const float* w1  = (const float*)d_in[6];
  const float* g1  = (const float*)d_in[8];
  const float* be1 = (const float*)d_in[9];
  const float* w2  = (const float*)d_in[10];
  const float* g2  = (const float*)d_in[12];
  const float* be2 = (const float*)d_in[13];

  float* out = (float*)d_out;
  float* newxyz = out;                    // [B,S,3]
  float* pooled = out + (size_t)NB*NS*3;  // [B,S,128]

  float* ws = (float*)d_ws;
  float* pp     = ws;                                 // 65536
  int*   idx    = (int*)(ws + 65536);                 // 524288 ints
  float* part   = ws + 65536 + 524288;                // 512*128*2 = 131072
  float* statsF = part + 131072;                      // 768
  float* maxb   = statsF + 768;                       // 2097152
  float* minb   = maxb + 2097152;                     // 2097152

  k_fps<<<NB, 256, 0, stream>>>(xyz, pp, newxyz);
  k_bq<<<4096, 256, 0, stream>>>(xyz, pp, newxyz, idx);
  k_l0stats<<<512, 256, 0, stream>>>(xyz, pts, newxyz, idx, w0, part);
  k_fin<<<1, 128, 0, stream>>>(part, 512, g0, be0, statsF, 0, 64);
  k_l1stats<<<512, 256, 0, stream>>>(xyz, pts, newxyz, idx, w0, w1, statsF, part);
  k_fin<<<1, 128, 0, stream>>>(part, 512, g1, be1, statsF, 1, 64);
  k_l2<<<256, 256, 0, stream>>>(xyz, pts, newxyz, idx, w0, w1, w2, statsF, part, maxb, minb);
  k_fin<<<1, 128, 0, stream>>>(part, 256, g2, be2, statsF, 2, 128);
  k_pool<<<8192, 256, 0, stream>>>(maxb, minb, statsF, pooled);
}